// Round 8
// baseline (16513.937 us; speedup 1.0000x reference)
//
#include <hip/hip_runtime.h>
#include <hip/hip_fp16.h>

// APDL_RNN: allpass-delay LSTM. B=32, T=8192, I=1, H=256, OS_FACTOR=1.5 -> coeff=1/3.
// 128 WGs = 32 batches x 4 quartet members; 512 threads/WG (8 waves).
// GEMV: each WG owns 64 hidden units (256 gate rows), K-split across lane pairs;
// 128 fp32 weights/thread as 32 pinned floatx4 (proven R5; VGPR_Count=88 = weights
// in unified-file AGPRs, read directly by VALU). hs padded: 0 bank conflicts.
//
// R8 restructure (R7 lesson: IC hop is irreducible; shorten everything around it):
//  - Writers publish RAW GATES immediately after the dot: 4 fp16 gates + embedded
//    tags in one 16B slot = two 8B atoms [tag | g0g1] [tag | g2g3], agent scope.
//  - Readers (256 threads/WG, one per unit) replicate the act/LSTM/allpass state
//    update for ALL units from the same published bits -> bitwise identical
//    across WGs, deterministic. Owner WG writes outputs.
//  - 2-deep pipelined poll on the single 16B address (vmcnt(1) rotation) halves
//    catch granularity vs a serial spin.
//  - hs parity-double-buffered -> one barrier per step.

#define Bn 32
#define Tn 8192
#define Hn 256
#define HPAD 136  // second K-half offset in padded hs

typedef float floatx4 __attribute__((ext_vector_type(4)));
typedef unsigned int uintx4 __attribute__((ext_vector_type(4)));

static constexpr float kCoeff = 1.0f / 3.0f;  // (1-alpha)/(1+alpha), alpha=0.5

__device__ __forceinline__ float sigf(float x) {
  return __builtin_amdgcn_rcpf(1.0f + __expf(-x));
}
__device__ __forceinline__ float tanhf_fast(float x) {
  return 1.0f - 2.0f * __builtin_amdgcn_rcpf(1.0f + __expf(2.0f * x));
}

// d_ws: ull pub[32][2][256][2] = 262144 B (16B slot per (batch,parity,unit):
// [tag|g0g1fp16][tag|g2g3fp16]); re-zeroed every launch so tags restart.
__global__ void init_ws(unsigned int* ws) {
  int i = blockIdx.x * 256 + threadIdx.x;
  if (i < 65536) ws[i] = 0;
}

#define LOADW(i) floatx4 w##i = *(const floatx4*)(wrow + 4 * (i))
#define PINW(i) asm volatile("" : "+v"(w##i))
#define ACC8(i, j, K)                                           \
  {                                                             \
    floatx4 p = *(const floatx4*)&hsp[(K)];                     \
    floatx4 q = *(const floatx4*)&hsp[(K) + 4];                 \
    a0 = fmaf(w##i[0], p[0], a0); a1 = fmaf(w##i[1], p[1], a1); \
    a2 = fmaf(w##i[2], p[2], a2); a3 = fmaf(w##i[3], p[3], a3); \
    a4 = fmaf(w##j[0], q[0], a4); a5 = fmaf(w##j[1], q[1], a5); \
    a6 = fmaf(w##j[2], q[2], a6); a7 = fmaf(w##j[3], q[3], a7); \
  }

// 2-deep pipelined poll of one 16B slot until both embedded tags == want.
// vmcnt(1) rotation gives ~latency/2 check granularity; "+v" on the waited
// register makes the tag check data-depend on the waitcnt (rule #18).
__device__ __forceinline__ uintx4 poll16(const unsigned long long* a8, unsigned want) {
  uintx4 va, vb, res;
  asm volatile("global_load_dwordx4 %0, %1, off sc0 sc1" : "=v"(va) : "v"(a8));
  for (;;) {
    asm volatile("global_load_dwordx4 %0, %1, off sc0 sc1" : "=v"(vb) : "v"(a8));
    asm volatile("s_waitcnt vmcnt(1)" : "+v"(va) :: "memory");
    if (va.x == want && va.z == want) { res = va; break; }
    asm volatile("global_load_dwordx4 %0, %1, off sc0 sc1" : "=v"(va) : "v"(a8));
    asm volatile("s_waitcnt vmcnt(1)" : "+v"(vb) :: "memory");
    if (vb.x == want && vb.z == want) { res = vb; break; }
  }
  asm volatile("s_waitcnt vmcnt(0)" : "+v"(va), "+v"(vb) :: "memory");  // drain stray load
  return res;
}

__global__ __launch_bounds__(512, 2) void apdl_rnn(
    const float* __restrict__ x, const float* __restrict__ W_ih,
    const float* __restrict__ W_hh, const float* __restrict__ b_ih,
    const float* __restrict__ b_hh, float* __restrict__ out,
    unsigned long long* __restrict__ pub) {
  const int bid = blockIdx.x;
  const int w = bid >> 5;     // quartet member 0..3
  const int b = bid & 31;     // batch
  const int tid = (int)threadIdx.x;
  const int hf = tid & 1;     // K-half
  const int p = tid >> 1;     // row-pair index 0..255
  const int g = p & 3;        // gate: 0=i 1=f 2=g 3=o (unused name kept for clarity)
  const int uG = w * 64 + (p >> 2);  // GEMV row's unit 0..255
  const int row = g * Hn + uG;

  __shared__ __align__(16) float xs[Tn];           // this batch's x sequence, 32KB
  __shared__ __align__(16) float hs2[2][2 * HPAD]; // parity-dbuf padded ap_h staging

  for (int i = tid; i < Tn; i += 512) xs[i] = x[b * Tn + i];

  // weights: 32 x floatx4, pinned once (unified VGPR/AGPR file) — proven R5
  const float* wrow = W_hh + row * Hn + hf * 128;
  LOADW(0);  LOADW(1);  LOADW(2);  LOADW(3);  LOADW(4);  LOADW(5);  LOADW(6);  LOADW(7);
  LOADW(8);  LOADW(9);  LOADW(10); LOADW(11); LOADW(12); LOADW(13); LOADW(14); LOADW(15);
  LOADW(16); LOADW(17); LOADW(18); LOADW(19); LOADW(20); LOADW(21); LOADW(22); LOADW(23);
  LOADW(24); LOADW(25); LOADW(26); LOADW(27); LOADW(28); LOADW(29); LOADW(30); LOADW(31);
  asm volatile("s_waitcnt vmcnt(0)" ::: "memory");
  PINW(0);  PINW(1);  PINW(2);  PINW(3);  PINW(4);  PINW(5);  PINW(6);  PINW(7);
  PINW(8);  PINW(9);  PINW(10); PINW(11); PINW(12); PINW(13); PINW(14); PINW(15);
  PINW(16); PINW(17); PINW(18); PINW(19); PINW(20); PINW(21); PINW(22); PINW(23);
  PINW(24); PINW(25); PINW(26); PINW(27); PINW(28); PINW(29); PINW(30); PINW(31);

  const float wih = W_ih[row];
  const float bias = b_ih[row] + b_hh[row];

  unsigned long long* mypub = pub + (size_t)b * 2 * Hn * 2;  // [parity][unit][2]

  // replicated per-unit recurrent state (threads tid<256; unit = tid)
  float s1h = 0.f, s1c = 0.f, aph = 0.f, apc = 0.f;

  for (int t = 0;; ++t) {
    // ---- preamble: reconstruct step t-1, produce ap(t), stage hs ----
    if (t == 0) {
      if (tid < Hn) hs2[0][tid + ((tid >> 7) << 3)] = 0.f;  // ap(0)=0
    } else {
      if (tid < Hn) {
        const int ur = tid;
        uintx4 pk = poll16(mypub + ((size_t)(t & 1) * Hn + ur) * 2, (unsigned)t);
        float gi = __half2float(__ushort_as_half((unsigned short)(pk.y & 0xffff)));
        float gf = __half2float(__ushort_as_half((unsigned short)(pk.y >> 16)));
        float gg = __half2float(__ushort_as_half((unsigned short)(pk.w & 0xffff)));
        float go = __half2float(__ushort_as_half((unsigned short)(pk.w >> 16)));
        float ai = sigf(gi), af = sigf(gf), ag = tanhf_fast(gg), ao = sigf(go);
        float c_new = af * apc + ai * ag;          // LSTM c-input is allpass-filtered apc
        float h_new = ao * tanhf_fast(c_new);
        if (t < Tn) {
          // allpass: ap(t) = coeff*(s(t-1) - ap(t-1)) + s(t-2); stage ap_h(t)
          float nh = kCoeff * (h_new - aph) + s1h;
          float nc = kCoeff * (c_new - apc) + s1c;
          s1h = h_new; s1c = c_new; aph = nh; apc = nc;
          hs2[t & 1][ur + ((ur >> 7) << 3)] = nh;
        }
        // outputs for step t-1, owner WG only
        if ((ur >> 6) == w) {
          int o = (b * Tn + (t - 1)) * Hn + ur;
          out[o] = h_new;                  // y
          out[67108864 + o] = h_new;       // states h
          out[134217728 + o] = c_new;      // states c
          if (t == Tn) {                   // ap_final = ap used at step Tn-1 (pre-update)
            out[201326592 + b * 512 + ur] = aph;
            out[201326592 + b * 512 + 256 + ur] = apc;
          }
        }
      }
      if (t == Tn) break;  // uniform exit
    }
    __syncthreads();  // hs(t) staged; single barrier per step (parity dbuf)

    // ---- GEMV(t): half-row dot, weights register-resident ----
    const float* hsp = &hs2[t & 1][hf * HPAD];
    float a0 = 0.f, a1 = 0.f, a2 = 0.f, a3 = 0.f;
    float a4 = 0.f, a5 = 0.f, a6 = 0.f, a7 = 0.f;
    ACC8(0, 1, 0);     ACC8(2, 3, 8);     ACC8(4, 5, 16);    ACC8(6, 7, 24);
    ACC8(8, 9, 32);    ACC8(10, 11, 40);  ACC8(12, 13, 48);  ACC8(14, 15, 56);
    ACC8(16, 17, 64);  ACC8(18, 19, 72);  ACC8(20, 21, 80);  ACC8(22, 23, 88);
    ACC8(24, 25, 96);  ACC8(26, 27, 104); ACC8(28, 29, 112); ACC8(30, 31, 120);
    float half_ = ((a0 + a1) + (a2 + a3)) + ((a4 + a5) + (a6 + a7));
    float dot = half_ + __shfl_xor(half_, 1);        // combine K-halves
    float raw = dot + xs[t] * wih + bias;            // raw gate pre-activation

    // ---- gather 4 raw gates to the unit's base lane, publish fp16-packed ----
    float orow = __shfl_xor(raw, 2);                 // neighbor gate row (same hf)
    unsigned lo16 = (unsigned)__half_as_ushort(__float2half(raw));
    unsigned hi16 = (unsigned)__half_as_ushort(__float2half(orow));
    unsigned p01 = lo16 | (hi16 << 16);              // on p%4==0 lanes: (g0,g1)
    unsigned p23 = __shfl_xor(p01, 4);               // from p+2 lane: (g2,g3)
    if ((tid & 7) == 0) {                            // one publisher per unit, hf==0
      unsigned tag = (unsigned)(t + 1);
      unsigned long long* ps = mypub + ((size_t)((t + 1) & 1) * Hn + uG) * 2;
      __hip_atomic_store(ps, (unsigned long long)tag | ((unsigned long long)p01 << 32),
                         __ATOMIC_RELAXED, __HIP_MEMORY_SCOPE_AGENT);
      __hip_atomic_store(ps + 1, (unsigned long long)tag | ((unsigned long long)p23 << 32),
                         __ATOMIC_RELAXED, __HIP_MEMORY_SCOPE_AGENT);
    }
  }
}

extern "C" void kernel_launch(void* const* d_in, const int* in_sizes, int n_in,
                              void* d_out, int out_size, void* d_ws, size_t ws_size,
                              hipStream_t stream) {
  const float* x = (const float*)d_in[0];
  const float* W_ih = (const float*)d_in[1];
  const float* W_hh = (const float*)d_in[2];
  const float* b_ih = (const float*)d_in[3];
  const float* b_hh = (const float*)d_in[4];
  float* out = (float*)d_out;
  unsigned long long* pub = (unsigned long long*)d_ws;

  init_ws<<<256, 256, 0, stream>>>((unsigned int*)d_ws);  // reset tags every launch
  apdl_rnn<<<128, 512, 0, stream>>>(x, W_ih, W_hh, b_ih, b_hh, out, pub);
}

// Round 10
// 14512.041 us; speedup vs baseline: 1.1379x; 1.1379x over previous
//
#include <hip/hip_runtime.h>

// APDL_RNN: allpass-delay LSTM. B=32, T=8192, I=1, H=256, OS_FACTOR=1.5 -> coeff=1/3.
// 128 WGs = 32 batches x 4 quartet members; 512 threads/WG (8 waves).
// Each WG owns 64 hidden units (256 gate rows); each gate row K-split across a lane
// pair: 128 fp32 weights/thread as 32 pinned floatx4 (unified VGPR/AGPR file).
// hs padded (+HPAD): 0 bank conflicts (R5).
//
// Sync memory model (R5-R9, 4-experiment-validated):
//   agent atomic store -> IC, does NOT invalidate remote L2 (R9 deadlock);
//   sc0-only poll -> permanently stale (R9); hand-rolled sc0+sc1 poll -> HBM-latency
//   spins (R8 FETCH x3). ONLY proven poll: __hip_atomic_load(AGENT) (R5).
// R10: (a) 4-deep pipelined poll in pure C++ (compiler emits partial vmcnt waits,
// catch ~150cyc vs ~600 serial); (b) parity-dbuf hs2, ONE barrier/step;
// (c) own-chunk LDS shortcut: publisher ds_writes own 64 units' ap_h directly,
// pollers handle only the 192 remote units.

#define Bn 32
#define Tn 8192
#define Hn 256
#define HPAD 136  // second K-half offset in padded hs

typedef float floatx4 __attribute__((ext_vector_type(4)));

static constexpr float kCoeff = 1.0f / 3.0f;  // (1-alpha)/(1+alpha), alpha=0.5

__device__ __forceinline__ float sigf(float x) {
  return __builtin_amdgcn_rcpf(1.0f + __expf(-x));
}
__device__ __forceinline__ float tanhf_fast(float x) {
  return 1.0f - 2.0f * __builtin_amdgcn_rcpf(1.0f + __expf(2.0f * x));
}
__device__ __forceinline__ float pick4(int d, float v0, float v1, float v2, float v3) {
  float r = (d == 0) ? v0 : v1;
  r = (d == 2) ? v2 : r;
  r = (d == 3) ? v3 : r;
  return r;
}
__device__ __forceinline__ unsigned long long ld_agent(const unsigned long long* p) {
  return __hip_atomic_load(p, __ATOMIC_RELAXED, __HIP_MEMORY_SCOPE_AGENT);
}

// d_ws: ull pub[32][2][256] = 131072 B (tag low32 | float bits high32); re-zeroed
// every launch so tags restart from 0.
__global__ void init_ws(unsigned int* ws) {
  int i = blockIdx.x * 256 + threadIdx.x;
  if (i < 32768) ws[i] = 0;
}

#define LOADW(i) floatx4 w##i = *(const floatx4*)(wrow + 4 * (i))
#define PINW(i) asm volatile("" : "+v"(w##i))
#define ACC8(i, j, K)                                           \
  {                                                             \
    floatx4 p = *(const floatx4*)&hsp[(K)];                     \
    floatx4 q = *(const floatx4*)&hsp[(K) + 4];                 \
    a0 = fmaf(w##i[0], p[0], a0); a1 = fmaf(w##i[1], p[1], a1); \
    a2 = fmaf(w##i[2], p[2], a2); a3 = fmaf(w##i[3], p[3], a3); \
    a4 = fmaf(w##j[0], q[0], a4); a5 = fmaf(w##j[1], q[1], a5); \
    a6 = fmaf(w##j[2], q[2], a6); a7 = fmaf(w##j[3], q[3], a7); \
  }

__global__ __launch_bounds__(512, 2) void apdl_rnn(
    const float* __restrict__ x, const float* __restrict__ W_ih,
    const float* __restrict__ W_hh, const float* __restrict__ b_ih,
    const float* __restrict__ b_hh, float* __restrict__ out,
    unsigned long long* __restrict__ pub) {
  const int bid = blockIdx.x;
  const int w = bid >> 5;    // quartet member 0..3
  const int b = bid & 31;    // batch
  const int tid = (int)threadIdx.x;
  const int hf = tid & 1;    // K-half
  const int p = tid >> 1;    // row-pair index 0..255
  const int g = p & 3;       // gate: 0=i 1=f 2=g 3=o
  const int ul = p >> 2;     // local hidden unit 0..63
  const int u = w * 64 + ul; // global hidden unit 0..255
  const int row = g * Hn + u;

  __shared__ __align__(16) float xs[Tn];            // this batch's x sequence, 32KB
  __shared__ __align__(16) float hs2[2][2 * HPAD];  // parity-dbuf padded ap_h staging

  for (int i = tid; i < Tn; i += 512) xs[i] = x[b * Tn + i];

  // this thread's half-row: 32 x floatx4, pinned once (unified VGPR/AGPR file)
  const float* wrow = W_hh + row * Hn + hf * 128;
  LOADW(0);  LOADW(1);  LOADW(2);  LOADW(3);  LOADW(4);  LOADW(5);  LOADW(6);  LOADW(7);
  LOADW(8);  LOADW(9);  LOADW(10); LOADW(11); LOADW(12); LOADW(13); LOADW(14); LOADW(15);
  LOADW(16); LOADW(17); LOADW(18); LOADW(19); LOADW(20); LOADW(21); LOADW(22); LOADW(23);
  LOADW(24); LOADW(25); LOADW(26); LOADW(27); LOADW(28); LOADW(29); LOADW(30); LOADW(31);
  asm volatile("s_waitcnt vmcnt(0)" ::: "memory");
  PINW(0);  PINW(1);  PINW(2);  PINW(3);  PINW(4);  PINW(5);  PINW(6);  PINW(7);
  PINW(8);  PINW(9);  PINW(10); PINW(11); PINW(12); PINW(13); PINW(14); PINW(15);
  PINW(16); PINW(17); PINW(18); PINW(19); PINW(20); PINW(21); PINW(22); PINW(23);
  PINW(24); PINW(25); PINW(26); PINW(27); PINW(28); PINW(29); PINW(30); PINW(31);

  const float wih = W_ih[row];
  const float bias = b_ih[row] + b_hh[row];

  unsigned long long* mypub = pub + b * 2 * Hn;  // [parity][unit]

  // poller role: threads 0..255 handle unit==tid, but only REMOTE units
  // (own 64 units are staged via LDS by the publisher lane — no IC trip).
  const bool poller = (tid < Hn) && ((tid >> 6) != w);

  float s1_h = 0.f, s1_c = 0.f, ap_h = 0.f, ap_c = 0.f;

  for (int t = 0; t < Tn; ++t) {
    // ---- acquire ap_h(t) for remote units: 4-deep pipelined agent poll ----
    if (t == 0) {
      if (tid < Hn) hs2[0][tid + ((tid >> 7) << 3)] = 0.f;  // ap(0) = 0
    } else if (poller) {
      const unsigned long long* pa = mypub + (t & 1) * Hn + tid;
      const unsigned want = (unsigned)t;
      unsigned long long v0 = ld_agent(pa);
      unsigned long long v1 = ld_agent(pa);
      unsigned long long v2 = ld_agent(pa);
      unsigned long long v3 = ld_agent(pa);
      unsigned long long pk;
      for (;;) {
        if ((unsigned)v0 == want) { pk = v0; break; }
        v0 = ld_agent(pa);
        if ((unsigned)v1 == want) { pk = v1; break; }
        v1 = ld_agent(pa);
        if ((unsigned)v2 == want) { pk = v2; break; }
        v2 = ld_agent(pa);
        if ((unsigned)v3 == want) { pk = v3; break; }
        v3 = ld_agent(pa);
      }
      hs2[t & 1][tid + ((tid >> 7) << 3)] = __uint_as_float((unsigned int)(pk >> 32));
    }
    __syncthreads();  // single barrier per step (parity dbuf)

    // ---- half-row dot: 128 fp32 MACs, weights register-resident ----
    const float* hsp = &hs2[t & 1][hf * HPAD];
    float a0 = 0.f, a1 = 0.f, a2 = 0.f, a3 = 0.f;
    float a4 = 0.f, a5 = 0.f, a6 = 0.f, a7 = 0.f;
    ACC8(0, 1, 0);     ACC8(2, 3, 8);     ACC8(4, 5, 16);    ACC8(6, 7, 24);
    ACC8(8, 9, 32);    ACC8(10, 11, 40);  ACC8(12, 13, 48);  ACC8(14, 15, 56);
    ACC8(16, 17, 64);  ACC8(18, 19, 72);  ACC8(20, 21, 80);  ACC8(22, 23, 88);
    ACC8(24, 25, 96);  ACC8(26, 27, 104); ACC8(28, 29, 112); ACC8(30, 31, 120);
    float half = ((a0 + a1) + (a2 + a3)) + ((a4 + a5) + (a6 + a7));
    float dot = half + __shfl_xor(half, 1);  // combine K-halves
    float raw = dot + xs[t] * wih + bias;

    // ---- activate own gate, exchange across the 4 gate pairs ----
    float act = (g == 2) ? tanhf_fast(raw) : sigf(raw);
    float v1 = __shfl_xor(act, 2);
    float v2 = __shfl_xor(act, 4);
    float v3 = __shfl_xor(act, 6);
    float ai = pick4(g,     act, v1, v2, v3);  // sigmoid(i)
    float af = pick4(g ^ 1, act, v1, v2, v3);  // sigmoid(f)
    float ag = pick4(g ^ 2, act, v1, v2, v3);  // tanh(g)
    float ao = pick4(g ^ 3, act, v1, v2, v3);  // sigmoid(o)

    float c_new = af * ap_c + ai * ag;
    float h_new = ao * tanhf_fast(c_new);

    if (t < Tn - 1) {
      // ---- allpass update + publish (latency-critical, before output stores) ----
      float nh = kCoeff * (h_new - ap_h) + s1_h;
      float nc = kCoeff * (c_new - ap_c) + s1_c;
      s1_h = h_new; s1_c = c_new; ap_h = nh; ap_c = nc;
      if (g == 3 && hf == 0) {
        unsigned long long pk =
            ((unsigned long long)__float_as_uint(nh) << 32) | (unsigned int)(t + 1);
        __hip_atomic_store(mypub + ((t + 1) & 1) * Hn + u, pk, __ATOMIC_RELAXED,
                           __HIP_MEMORY_SCOPE_AGENT);  // remote WGs (IC)
        hs2[(t + 1) & 1][u + ((u >> 7) << 3)] = nh;     // own WG (LDS shortcut)
      }
    } else {
      if (g == 0 && hf == 0)      out[201326592 + b * 512 + u] = ap_h;        // ap_final h
      else if (g == 1 && hf == 0) out[201326592 + b * 512 + 256 + u] = ap_c;  // ap_final c
    }

    // ---- outputs: (y, states_h, states_c) fp32, fire-and-forget ----
    int o = (b * Tn + t) * Hn + u;
    if (hf == 0) {
      if (g == 0)      out[o] = h_new;             // y
      else if (g == 2) out[67108864 + o] = h_new;  // states h
      else if (g == 1) out[134217728 + o] = c_new; // states c
    }
    // no trailing barrier: parity dbuf + publish-after-barrier make it safe
  }
}

extern "C" void kernel_launch(void* const* d_in, const int* in_sizes, int n_in,
                              void* d_out, int out_size, void* d_ws, size_t ws_size,
                              hipStream_t stream) {
  const float* x = (const float*)d_in[0];
  const float* W_ih = (const float*)d_in[1];
  const float* W_hh = (const float*)d_in[2];
  const float* b_ih = (const float*)d_in[3];
  const float* b_hh = (const float*)d_in[4];
  float* out = (float*)d_out;
  unsigned long long* pub = (unsigned long long*)d_ws;

  init_ws<<<128, 256, 0, stream>>>((unsigned int*)d_ws);  // reset tags every launch
  apdl_rnn<<<128, 512, 0, stream>>>(x, W_ih, W_hh, b_ih, b_hh, out, pub);
}

// Round 11
// 10755.679 us; speedup vs baseline: 1.5354x; 1.3492x over previous
//
#include <hip/hip_runtime.h>

// APDL_RNN: allpass-delay LSTM. B=32, T=8192, I=1, H=256, OS_FACTOR=1.5 -> coeff=1/3.
// 128 WGs = 32 batches x 4 quartet members; 512 threads/WG (8 waves).
// Each WG owns 64 hidden units (256 gate rows); each gate row K-split across a lane
// pair: 128 fp32 weights/thread as 32 pinned floatx4 (unified VGPR/AGPR file).
// hs padded (+HPAD): 0 bank conflicts (R5).
//
// Sync memory model (R5-R10, 5-experiment-validated):
//   ONLY proven poll: serial __hip_atomic_load(AGENT) (R5, 11.3ms).
//   agent store does NOT invalidate remote L2 (R9 deadlock: sc0-only poll);
//   hand-rolled sc0+sc1 poll -> HBM-class spins (R8, FETCH x3, +5ms);
//   DEEPER polling poisons the IC (R10: 4-deep pipelined poll, FETCH +55MB, +3ms).
// R11 = R5 + two isolated safe cuts (R10 bundled them with the bad poll):
//   (a) parity-dbuf hs2 -> ONE barrier/step; (b) own-chunk LDS shortcut: publisher
//   ds_writes its own unit's ap_h; only 192 remote units polled (-25% IC traffic).

#define Bn 32
#define Tn 8192
#define Hn 256
#define HPAD 136  // second K-half offset in padded hs

typedef float floatx4 __attribute__((ext_vector_type(4)));

static constexpr float kCoeff = 1.0f / 3.0f;  // (1-alpha)/(1+alpha), alpha=0.5

__device__ __forceinline__ float sigf(float x) {
  return __builtin_amdgcn_rcpf(1.0f + __expf(-x));
}
__device__ __forceinline__ float tanhf_fast(float x) {
  return 1.0f - 2.0f * __builtin_amdgcn_rcpf(1.0f + __expf(2.0f * x));
}
__device__ __forceinline__ float pick4(int d, float v0, float v1, float v2, float v3) {
  float r = (d == 0) ? v0 : v1;
  r = (d == 2) ? v2 : r;
  r = (d == 3) ? v3 : r;
  return r;
}

// d_ws: ull pub[32][2][256] = 131072 B (tag low32 | float bits high32); re-zeroed
// every launch so tags restart from 0.
__global__ void init_ws(unsigned int* ws) {
  int i = blockIdx.x * 256 + threadIdx.x;
  if (i < 32768) ws[i] = 0;
}

#define LOADW(i) floatx4 w##i = *(const floatx4*)(wrow + 4 * (i))
#define PINW(i) asm volatile("" : "+v"(w##i))
#define ACC8(i, j, K)                                           \
  {                                                             \
    floatx4 p = *(const floatx4*)&hsp[(K)];                     \
    floatx4 q = *(const floatx4*)&hsp[(K) + 4];                 \
    a0 = fmaf(w##i[0], p[0], a0); a1 = fmaf(w##i[1], p[1], a1); \
    a2 = fmaf(w##i[2], p[2], a2); a3 = fmaf(w##i[3], p[3], a3); \
    a4 = fmaf(w##j[0], q[0], a4); a5 = fmaf(w##j[1], q[1], a5); \
    a6 = fmaf(w##j[2], q[2], a6); a7 = fmaf(w##j[3], q[3], a7); \
  }

__global__ __launch_bounds__(512, 2) void apdl_rnn(
    const float* __restrict__ x, const float* __restrict__ W_ih,
    const float* __restrict__ W_hh, const float* __restrict__ b_ih,
    const float* __restrict__ b_hh, float* __restrict__ out,
    unsigned long long* __restrict__ pub) {
  const int bid = blockIdx.x;
  const int w = bid >> 5;    // quartet member 0..3
  const int b = bid & 31;    // batch
  const int tid = (int)threadIdx.x;
  const int hf = tid & 1;    // K-half
  const int p = tid >> 1;    // row-pair index 0..255
  const int g = p & 3;       // gate: 0=i 1=f 2=g 3=o
  const int ul = p >> 2;     // local hidden unit 0..63
  const int u = w * 64 + ul; // global hidden unit 0..255
  const int row = g * Hn + u;

  __shared__ __align__(16) float xs[Tn];            // this batch's x sequence, 32KB
  __shared__ __align__(16) float hs2[2][2 * HPAD];  // parity-dbuf padded ap_h staging

  for (int i = tid; i < Tn; i += 512) xs[i] = x[b * Tn + i];

  // this thread's half-row: 32 x floatx4, pinned once (unified VGPR/AGPR file)
  const float* wrow = W_hh + row * Hn + hf * 128;
  LOADW(0);  LOADW(1);  LOADW(2);  LOADW(3);  LOADW(4);  LOADW(5);  LOADW(6);  LOADW(7);
  LOADW(8);  LOADW(9);  LOADW(10); LOADW(11); LOADW(12); LOADW(13); LOADW(14); LOADW(15);
  LOADW(16); LOADW(17); LOADW(18); LOADW(19); LOADW(20); LOADW(21); LOADW(22); LOADW(23);
  LOADW(24); LOADW(25); LOADW(26); LOADW(27); LOADW(28); LOADW(29); LOADW(30); LOADW(31);
  asm volatile("s_waitcnt vmcnt(0)" ::: "memory");
  PINW(0);  PINW(1);  PINW(2);  PINW(3);  PINW(4);  PINW(5);  PINW(6);  PINW(7);
  PINW(8);  PINW(9);  PINW(10); PINW(11); PINW(12); PINW(13); PINW(14); PINW(15);
  PINW(16); PINW(17); PINW(18); PINW(19); PINW(20); PINW(21); PINW(22); PINW(23);
  PINW(24); PINW(25); PINW(26); PINW(27); PINW(28); PINW(29); PINW(30); PINW(31);

  const float wih = W_ih[row];
  const float bias = b_ih[row] + b_hh[row];

  unsigned long long* mypub = pub + b * 2 * Hn;  // [parity][unit]

  // pollers: threads 0..255 handle unit==tid, but only REMOTE units
  // (own 64 units arrive via the publisher's LDS shortcut — no IC trip).
  const bool poller = (tid < Hn) && ((tid >> 6) != w);

  float s1_h = 0.f, s1_c = 0.f, ap_h = 0.f, ap_c = 0.f;

  for (int t = 0; t < Tn; ++t) {
    // ---- acquire ap_h(t) for remote units: serial agent poll (R5-proven) ----
    if (t == 0) {
      if (tid < Hn) hs2[0][tid + ((tid >> 7) << 3)] = 0.f;  // ap(0) = 0
    } else if (poller) {
      const unsigned long long* pa = mypub + (t & 1) * Hn + tid;
      unsigned long long pk;
      do {
        pk = __hip_atomic_load(pa, __ATOMIC_RELAXED, __HIP_MEMORY_SCOPE_AGENT);
      } while ((unsigned int)pk != (unsigned int)t);
      hs2[t & 1][tid + ((tid >> 7) << 3)] = __uint_as_float((unsigned int)(pk >> 32));
    }
    __syncthreads();  // single barrier per step (parity dbuf)

    // ---- half-row dot: 128 fp32 MACs, weights register-resident ----
    const float* hsp = &hs2[t & 1][hf * HPAD];
    float a0 = 0.f, a1 = 0.f, a2 = 0.f, a3 = 0.f;
    float a4 = 0.f, a5 = 0.f, a6 = 0.f, a7 = 0.f;
    ACC8(0, 1, 0);     ACC8(2, 3, 8);     ACC8(4, 5, 16);    ACC8(6, 7, 24);
    ACC8(8, 9, 32);    ACC8(10, 11, 40);  ACC8(12, 13, 48);  ACC8(14, 15, 56);
    ACC8(16, 17, 64);  ACC8(18, 19, 72);  ACC8(20, 21, 80);  ACC8(22, 23, 88);
    ACC8(24, 25, 96);  ACC8(26, 27, 104); ACC8(28, 29, 112); ACC8(30, 31, 120);
    float half = ((a0 + a1) + (a2 + a3)) + ((a4 + a5) + (a6 + a7));
    float dot = half + __shfl_xor(half, 1);  // combine K-halves
    float raw = dot + xs[t] * wih + bias;

    // ---- activate own gate, exchange across the 4 gate pairs ----
    float act = (g == 2) ? tanhf_fast(raw) : sigf(raw);
    float v1 = __shfl_xor(act, 2);
    float v2 = __shfl_xor(act, 4);
    float v3 = __shfl_xor(act, 6);
    float ai = pick4(g,     act, v1, v2, v3);  // sigmoid(i)
    float af = pick4(g ^ 1, act, v1, v2, v3);  // sigmoid(f)
    float ag = pick4(g ^ 2, act, v1, v2, v3);  // tanh(g)
    float ao = pick4(g ^ 3, act, v1, v2, v3);  // sigmoid(o)

    float c_new = af * ap_c + ai * ag;
    float h_new = ao * tanhf_fast(c_new);

    if (t < Tn - 1) {
      // ---- allpass h-update + publish FIRST (latency-critical) ----
      float nh = kCoeff * (h_new - ap_h) + s1_h;
      if (g == 3 && hf == 0) {
        unsigned long long pk =
            ((unsigned long long)__float_as_uint(nh) << 32) | (unsigned int)(t + 1);
        __hip_atomic_store(mypub + ((t + 1) & 1) * Hn + u, pk, __ATOMIC_RELAXED,
                           __HIP_MEMORY_SCOPE_AGENT);  // remote WGs (IC)
        hs2[(t + 1) & 1][u + ((u >> 7) << 3)] = nh;     // own WG (LDS shortcut)
      }
      float nc = kCoeff * (c_new - ap_c) + s1_c;
      s1_h = h_new; s1_c = c_new; ap_h = nh; ap_c = nc;
    } else {
      if (g == 0 && hf == 0)      out[201326592 + b * 512 + u] = ap_h;        // ap_final h
      else if (g == 1 && hf == 0) out[201326592 + b * 512 + 256 + u] = ap_c;  // ap_final c
    }

    // ---- outputs: (y, states_h, states_c) fp32, fire-and-forget ----
    int o = (b * Tn + t) * Hn + u;
    if (hf == 0) {
      if (g == 0)      out[o] = h_new;             // y
      else if (g == 2) out[67108864 + o] = h_new;  // states h
      else if (g == 1) out[134217728 + o] = c_new; // states c
    }
    // no trailing barrier: parity dbuf + publish-after-barrier make it safe
  }
}

extern "C" void kernel_launch(void* const* d_in, const int* in_sizes, int n_in,
                              void* d_out, int out_size, void* d_ws, size_t ws_size,
                              hipStream_t stream) {
  const float* x = (const float*)d_in[0];
  const float* W_ih = (const float*)d_in[1];
  const float* W_hh = (const float*)d_in[2];
  const float* b_ih = (const float*)d_in[3];
  const float* b_hh = (const float*)d_in[4];
  float* out = (float*)d_out;
  unsigned long long* pub = (unsigned long long*)d_ws;

  init_ws<<<128, 256, 0, stream>>>((unsigned int*)d_ws);  // reset tags every launch
  apdl_rnn<<<128, 512, 0, stream>>>(x, W_ih, W_hh, b_ih, b_hh, out, pub);
}